// Round 8
// baseline (305.677 us; speedup 1.0000x reference)
//
#include <hip/hip_runtime.h>
#include <hip/hip_bf16.h>

#define SEQ   512
#define BATCH 128
#define FEAT  1024
#define EMBED 1024
#define NLANG 8

typedef __attribute__((ext_vector_type(8))) short bf16x8;
typedef __attribute__((ext_vector_type(4))) float f32x4;
typedef unsigned short ushort_t;

__device__ __forceinline__ unsigned pk2(float a, float b) {
  float2 f; f.x = a; f.y = b;
  __hip_bfloat162 h = __float22bfloat162_rn(f);   // v_cvt_pk_bf16_f32
  union { __hip_bfloat162 h2; unsigned u; } cv;
  cv.h2 = h;
  return cv.u;
}

__device__ __forceinline__ bf16x8 cvt8(float4 lo, float4 hi) {
  union { bf16x8 v; unsigned u[4]; } q;
  q.u[0] = pk2(lo.x, lo.y); q.u[1] = pk2(lo.z, lo.w);
  q.u[2] = pk2(hi.x, hi.y); q.u[3] = pk2(hi.z, hi.w);
  return q.v;
}

__device__ __forceinline__ void gld16(const void* g, void* l) {
  __builtin_amdgcn_global_load_lds(
      (const __attribute__((address_space(1))) void*)g,
      (__attribute__((address_space(3))) void*)l, 16, 0, 0);
}

// ---------------- Pass 1 (W only): f32 -> bf16, linear. ~48 MB traffic. -----
__global__ __launch_bounds__(256) void convert_w_kernel(
    const float* __restrict__ Wf, ushort_t* __restrict__ Wbf)
{
  const int n = (NLANG * EMBED * FEAT) / 4;
  for (int c = blockIdx.x * 256 + threadIdx.x; c < n; c += gridDim.x * 256) {
    float4 v = ((const float4*)Wf)[c];
    uint2 o; o.x = pk2(v.x, v.y); o.y = pk2(v.z, v.w);
    *(uint2*)(Wbf + ((size_t)c << 2)) = o;
  }
}

// ---------------- Pass 2: fused grouped GEMM -------------------------------
// 256x256 tile, BK=32 granules. A: f32 gathered into a 2-DEEP register
// pipeline (load at g for g+2; cvt+ds_write at g+1 AFTER the MFMA cluster ->
// compiler wait is vmcnt(8), B pipeline stays 1-granule deep). A LDS = R4's
// measured-clean bf16 ring-2 layout. B: bf16 gld16 ring-3 (R4-verified).
// End-of-granule: vmcnt(6) lgkmcnt(0) retires exactly B(g+1) + A ds_writes.
// 512 threads = 8 waves (2M x 4N); wave = 128x64 via acc[8][4].
__global__ __launch_bounds__(512, 2) void grouped_gemm_fused(
    const float* __restrict__ feat,    // [S*B, F] f32 (original order)
    const ushort_t* __restrict__ Wbf,  // [L, E, F] bf16
    const float* __restrict__ bias,    // [L, E]
    const int*   __restrict__ toks,    // [B]
    float*       __restrict__ out)     // [S*B, E] original order
{
  extern __shared__ char ldsraw[];                 // 81920 B dynamic
  ushort_t* Af = (ushort_t*)ldsraw;                // 2 bufs x 16 KiB (bf16)
  ushort_t* Bf = (ushort_t*)(ldsraw + 32768);      // 3 bufs x 16 KiB (bf16)
  __shared__ int tokarr[128];
  __shared__ unsigned long long ballots[2][8];
  __shared__ int perm[128];
  __shared__ int rowsrc[256];

  const int tid = threadIdx.x;
  const int l   = tid & 63;
  const int w   = tid >> 6;
  const int wr  = w >> 2;                    // 0..1 (M half)
  const int wc  = w & 3;                     // 0..3 (N quarter)

  // XCD-chunked bijective swizzle (1024 blocks = 8 XCDs x 128).
  const int bid = blockIdx.x;
  const int L   = (bid & 7) * 128 + (bid >> 3);
  const int et  = L & 3;
  const int mt  = (L >> 7) * 32 + ((L >> 2) & 31);
  const int m0  = mt * 256;
  const int e0  = et * 256;

  // ---- bucket setup (ballot histogram + rank; waves 0,1 vote) ----
  if (tid < 128) tokarr[tid] = toks[tid];
  __syncthreads();
  if (tid < 128) {
    int myt = tokarr[tid];
#pragma unroll
    for (int lg = 0; lg < 8; ++lg) {
      unsigned long long bl = __ballot(myt == lg);
      if (l == 0) ballots[w][lg] = bl;
    }
  }
  __syncthreads();

  int lsel = 0, base = 0, csel = 1, boff_sel = 0;
  {
    int cum = 0, boff = 0;
#pragma unroll
    for (int lg = 0; lg < 8; ++lg) {
      int c = __popcll(ballots[0][lg]) + __popcll(ballots[1][lg]);
      int seg = c << 9;
      bool in = (m0 >= cum) && (m0 < cum + seg);
      if (in) { lsel = lg; base = cum; csel = c; boff_sel = boff; }
      cum += seg; boff += c;
    }
  }

  if (tid < 128) {
    int myt = tokarr[tid];
    unsigned long long ltm = (1ull << l) - 1ull;
    int rank = (w == 0) ? __popcll(ballots[0][myt] & ltm)
                        : __popcll(ballots[0][myt]) + __popcll(ballots[1][myt] & ltm);
    int boff2 = 0;
#pragma unroll
    for (int lg = 0; lg < 8; ++lg) {
      int c = __popcll(ballots[0][lg]) + __popcll(ballots[1][lg]);
      boff2 += (lg < myt) ? c : 0;
    }
    perm[boff2 + rank] = tid;
  }
  __syncthreads();
  if (tid < 256) {
    int local = m0 - base + tid;
    int s = local / csel;
    int j = local - s * csel;
    rowsrc[tid] = s * BATCH + perm[boff_sel + j];
  }
  __syncthreads();

  // ---- A reg-staging: granule = 256 rows x 32 f32. Thread owns row=tid>>1,
  // 64B-half h=tid&1 (f32 k = h*16..h*16+15): 4x dwordx4, line-aligned.
  // After cvt: bf16 chunks cc = 2h, 2h+1 at LDS chunk row*4 + (cc^s),
  // s=(row>>1)&3 (R4 layout; write pattern measured clean in R7: 11K). ----
  const int arow = tid >> 1;
  const int ah   = tid & 1;
  const float* aSrcP = feat + (size_t)rowsrc[arow] * FEAT + ah * 16;
  const int sAw     = (arow >> 1) & 3;
  const int wchunk0 = arow * 4 + ((2 * ah) ^ sAw);
  const int wchunk1 = arow * 4 + ((2 * ah + 1) ^ sAw);
  // 2-deep A register pipeline (two named sets; parity-static via 6-unroll).
  float4 arA0, arA1, arA2, arA3;
  float4 arB0, arB1, arB2, arB3;

  // ---- B staging (R4-verified): c = row*4 + cc; src chunk = cc^((row>>1)&3).
  const int ca  = w * 128 + l;
  const int rwB = ca >> 2;
  const int ccB = ca & 3;
  const int sB  = (rwB >> 1) & 3;
  const ushort_t* bS0 = Wbf + ((size_t)lsel * EMBED + e0 + rwB) * FEAT + ((ccB ^ sB) * 8);
  const ushort_t* bS1 = bS0 + (size_t)16 * FEAT;
  const int bD0 = (w * 128) * 8;             // ushort units within a B buf
  const int bD1 = (w * 128 + 64) * 8;

  // ---- fragment read offsets (R4-verified, conflict-free) ----
  const int kc  = l >> 4;
  const int rA  = wr * 128 + (l & 15);
  const int aRd = rA * 32 + ((kc ^ ((rA >> 1) & 3)) * 8);
  const int rB  = wc * 64 + (l & 15);
  const int bRd = rB * 32 + ((kc ^ ((rB >> 1) & 3)) * 8);

  f32x4 acc[8][4] = {};

#define LOAD_A(kt, SET)                                                    \
  do { const float* _p = aSrcP + (kt) * 32;                                \
    if ((SET) == 0) {                                                      \
      arA0 = *(const float4*)(_p);      arA1 = *(const float4*)(_p + 4);   \
      arA2 = *(const float4*)(_p + 8);  arA3 = *(const float4*)(_p + 12);  \
    } else {                                                               \
      arB0 = *(const float4*)(_p);      arB1 = *(const float4*)(_p + 4);   \
      arB2 = *(const float4*)(_p + 8);  arB3 = *(const float4*)(_p + 12);  \
    } } while (0)
#define WRITE_A(buf, SET)                                                  \
  do { bf16x8* _wp = (bf16x8*)(Af + (buf) * 8192);                         \
    if ((SET) == 0) {                                                      \
      _wp[wchunk0] = cvt8(arA0, arA1);                                     \
      _wp[wchunk1] = cvt8(arA2, arA3);                                     \
    } else {                                                               \
      _wp[wchunk0] = cvt8(arB0, arB1);                                     \
      _wp[wchunk1] = cvt8(arB2, arB3);                                     \
    } } while (0)
#define STAGE_B(kt, buf)                                                   \
  do { const int _o = (kt) * 32;                                           \
    gld16(bS0 + _o, Bf + (buf) * 8192 + bD0);                              \
    gld16(bS1 + _o, Bf + (buf) * 8192 + bD1); } while (0)

// Granule G (J = G mod 6, compile-time). Reads A-buf J&1 and B-buf J%3.
// DOSTAGE: issue LOAD_A(G+2)->set J&1 + STAGE_B(G+2)->buf (J+2)%3 at START.
// DOCVT: after MFMA, cvt set (J+1)&1 -> A-buf (J+1)&1 (compiler waits
// vmcnt(8): exactly A(G+1); B(G+1)+granule-(G) stages stay in flight).
// ENDWAIT: vmcnt literal (+lgkmcnt(0)) before the end barrier.
#define GRAN(G, J, DOCVT, DOSTAGE, ENDWAIT, ENDBAR)                        \
  do {                                                                     \
    if (DOSTAGE) { LOAD_A((G) + 2, (J) & 1); STAGE_B((G) + 2, ((J) + 2) % 3); } \
    const ushort_t* Ar_ = Af + ((J) & 1) * 8192;                           \
    const ushort_t* Br_ = Bf + ((J) % 3) * 8192;                           \
    bf16x8 af[8], bfq[4];                                                  \
    _Pragma("unroll") for (int mf = 0; mf < 8; ++mf)                       \
        af[mf] = *(const bf16x8*)(Ar_ + aRd + mf * 512);                   \
    _Pragma("unroll") for (int nf = 0; nf < 4; ++nf)                       \
        bfq[nf] = *(const bf16x8*)(Br_ + bRd + nf * 512);                  \
    asm volatile("s_waitcnt lgkmcnt(0)" ::: "memory");                     \
    __builtin_amdgcn_sched_barrier(0);                                     \
    __builtin_amdgcn_s_setprio(1);                                         \
    _Pragma("unroll") for (int mf = 0; mf < 8; ++mf)                       \
        _Pragma("unroll") for (int nf = 0; nf < 4; ++nf)                   \
            acc[mf][nf] = __builtin_amdgcn_mfma_f32_16x16x32_bf16(         \
                af[mf], bfq[nf], acc[mf][nf], 0, 0, 0);                    \
    __builtin_amdgcn_s_setprio(0);                                         \
    if (DOCVT) { WRITE_A(((J) + 1) & 1, ((J) + 1) & 1); }                  \
    asm volatile(ENDWAIT ::: "memory");                                    \
    if (ENDBAR) { __builtin_amdgcn_s_barrier();                            \
                  __builtin_amdgcn_sched_barrier(0); }                     \
  } while (0)

  // ---- prologue ----
  LOAD_A(0, 0);                 // A(0) -> set 0
  STAGE_B(0, 0);
  LOAD_A(1, 1);                 // A(1) -> set 1
  STAGE_B(1, 1);
  WRITE_A(0, 0);                // cvt A(0) -> Abuf0 (compiler: vmcnt(8))
  __builtin_amdgcn_sched_barrier(0);
  // retire B(0) (leaves A(1)x4 + B(1)x2 = 6); drain Abuf0 ds_writes.
  asm volatile("s_waitcnt vmcnt(6) lgkmcnt(0)" ::: "memory");
  __builtin_amdgcn_s_barrier();
  __builtin_amdgcn_sched_barrier(0);

  // ---- main: granules 0..29 (J=g%6; A ring-2 = J&1, B ring-3 = J%3,
  // reg-set parity = J&1 — all periodic in 6). ----
#pragma unroll 1
  for (int gb = 0; gb < 30; gb += 6) {
    GRAN(gb + 0, 0, true, true, "s_waitcnt vmcnt(6) lgkmcnt(0)", true);
    GRAN(gb + 1, 1, true, true, "s_waitcnt vmcnt(6) lgkmcnt(0)", true);
    GRAN(gb + 2, 2, true, true, "s_waitcnt vmcnt(6) lgkmcnt(0)", true);
    GRAN(gb + 3, 3, true, true, "s_waitcnt vmcnt(6) lgkmcnt(0)", true);
    GRAN(gb + 4, 4, true, true, "s_waitcnt vmcnt(6) lgkmcnt(0)", true);
    GRAN(gb + 5, 5, true, true, "s_waitcnt vmcnt(6) lgkmcnt(0)", true);
  }
  // tail: g30 (J=0): no stage; cvt A(31) (set 1) -> Abuf1; drain all B.
  GRAN(30, 0, true, false, "s_waitcnt vmcnt(0) lgkmcnt(0)", true);
  // g31 (J=1): compute only.
  GRAN(31, 1, false, false, "s_nop 0", false);

#undef GRAN
#undef LOAD_A
#undef WRITE_A
#undef STAGE_B

  // ---- epilogue: C/D col = lane&15 (-> e), row = (lane>>4)*4+j (-> m) ----
  const int col = l & 15;
  const int r4  = (l >> 4) * 4;
  float bvv[4];
#pragma unroll
  for (int nf = 0; nf < 4; ++nf)
    bvv[nf] = bias[lsel * EMBED + e0 + wc * 64 + nf * 16 + col];
#pragma unroll
  for (int mf = 0; mf < 8; ++mf) {
#pragma unroll
    for (int j = 0; j < 4; ++j) {
      const size_t ro = (size_t)rowsrc[wr * 128 + mf * 16 + r4 + j] * EMBED;
#pragma unroll
      for (int nf = 0; nf < 4; ++nf)
        out[ro + e0 + wc * 64 + nf * 16 + col] = acc[mf][nf][j] + bvv[nf];
    }
  }
}

// ---------------- Fallback (R2 fused kernel) if ws too small ----------------
__global__ __launch_bounds__(256, 2) void grouped_proj_fused(
    const float* __restrict__ feat, const float* __restrict__ Wt,
    const float* __restrict__ bias, const int* __restrict__ toks,
    float* __restrict__ out)
{
  __shared__ uint4 As[1024];
  __shared__ uint4 Bs[1024];
  __shared__ int tokarr[128];
  __shared__ unsigned long long ballots[2][8];
  __shared__ int perm[128];
  __shared__ int rowsrc[128];

  const int tid  = threadIdx.x;
  const int lane = tid & 63;
  const int wv   = tid >> 6;
  const int wr   = wv >> 1;
  const int wc   = wv & 1;
  const int bid = blockIdx.x;
  const int xcd = bid & 7;
  const int sq  = bid >> 3;
  const int et  = sq & 7;
  const int mt  = (sq >> 3) * 8 + xcd;
  const int m0  = mt * 128;
  const int e0  = et * 128;

  if (tid < 128) tokarr[tid] = toks[tid];
  __syncthreads();
  if (tid < 128) {
    int myt = tokarr[tid];
#pragma unroll
    for (int lg = 0; lg < 8; ++lg) {
      unsigned long long bl = __ballot(myt == lg);
      if (lane == 0) ballots[wv][lg] = bl;
    }
  }
  __syncthreads();
  int lsel = 0, base = 0, csel = 1, boff_sel = 0;
  {
    int cum = 0, boff = 0;
#pragma unroll
    for (int lg = 0; lg < 8; ++lg) {
      int c = __popcll(ballots[0][lg]) + __popcll(ballots[1][lg]);
      int seg = c << 9;
      bool in = (m0 >= cum) && (m0 < cum + seg);
      if (in) { lsel = lg; base = cum; csel = c; boff_sel = boff; }
      cum += seg; boff += c;
    }
  }
  if (tid < 128) {
    int myt = tokarr[tid];
    unsigned long long ltm = (1ull << lane) - 1ull;
    int rank = (wv == 0) ? __popcll(ballots[0][myt] & ltm)
                         : __popcll(ballots[0][myt]) + __popcll(ballots[1][myt] & ltm);
    int boff2 = 0;
#pragma unroll
    for (int lg = 0; lg < 8; ++lg) {
      int c = __popcll(ballots[0][lg]) + __popcll(ballots[1][lg]);
      boff2 += (lg < myt) ? c : 0;
    }
    perm[boff2 + rank] = tid;
  }
  __syncthreads();
  if (tid < 128) {
    int local = m0 - base + tid;
    int s = local / csel;
    int j = local - s * csel;
    rowsrc[tid] = s * BATCH + perm[boff_sel + j];
  }
  __syncthreads();

  int slot_i[4];
  const float* aptr[4];
  const float* bptr[4];
#pragma unroll
  for (int it = 0; it < 4; ++it) {
    int c    = it * 256 + tid;
    int kg   = c & 7;
    int row  = c >> 3;
    int ksub = kg & 3;
    int kk   = kg >> 2;
    int frag = row >> 4;
    slot_i[it] = (kk * 8 + frag) * 64 + ((row & 15) ^ (ksub << 1) ^ kk) + ksub * 16;
    aptr[it] = feat + (size_t)rowsrc[row] * FEAT + kg * 8;
    bptr[it] = Wt + ((size_t)lsel * EMBED + e0 + row) * FEAT + kg * 8;
  }

  f32x4 acc[4][4] = {};
  for (int k0 = 0; k0 < FEAT; k0 += 64) {
    __syncthreads();
#pragma unroll
    for (int it = 0; it < 4; ++it) {
      float4 alo = *(const float4*)(aptr[it] + k0);
      float4 ahi = *(const float4*)(aptr[it] + k0 + 4);
      uint4 av;
      av.x = pk2(alo.x, alo.y); av.y = pk2(alo.z, alo.w);
      av.z = pk2(ahi.x, ahi.y); av.w = pk2(ahi.z, ahi.w);
      As[slot_i[it]] = av;
      float4 blo = *(const float4*)(bptr[it] + k0);
      float4 bhi = *(const float4*)(bptr[it] + k0 + 4);
      uint4 bv;
      bv.x = pk2(blo.x, blo.y); bv.y = pk2(blo.z, blo.w);
      bv.z = pk2(bhi.x, bhi.y); bv.w = pk2(bhi.z, bhi.w);
      Bs[slot_i[it]] = bv;
    }
    __syncthreads();
#pragma unroll
    for (int kk = 0; kk < 2; ++kk) {
      const int ksr = lane >> 4;
      const int sw  = ((lane & 15) ^ (ksr << 1) ^ kk) + ksr * 16;
      bf16x8 af[4], bfr[4];
#pragma unroll
      for (int mi = 0; mi < 4; ++mi)
        af[mi] = ((const bf16x8*)As)[(kk * 8 + wr * 4 + mi) * 64 + sw];
#pragma unroll
      for (int ni = 0; ni < 4; ++ni)
        bfr[ni] = ((const bf16x8*)Bs)[(kk * 8 + wc * 4 + ni) * 64 + sw];
#pragma unroll
      for (int mi = 0; mi < 4; ++mi)
#pragma unroll
        for (int ni = 0; ni < 4; ++ni)
          acc[mi][ni] = __builtin_amdgcn_mfma_f32_16x16x32_bf16(
              af[mi], bfr[ni], acc[mi][ni], 0, 0, 0);
    }
  }

  const int col = lane & 15;
  const int r0  = (lane >> 4) * 4;
  float bvv[4];
#pragma unroll
  for (int ni = 0; ni < 4; ++ni)
    bvv[ni] = bias[lsel * EMBED + e0 + wc * 64 + ni * 16 + col];
#pragma unroll
  for (int mi = 0; mi < 4; ++mi) {
#pragma unroll
    for (int j = 0; j < 4; ++j) {
      const size_t ro = (size_t)rowsrc[wr * 64 + mi * 16 + r0 + j] * EMBED;
#pragma unroll
      for (int ni = 0; ni < 4; ++ni)
        out[ro + e0 + wc * 64 + ni * 16 + col] = acc[mi][ni][j] + bvv[ni];
    }
  }
}

extern "C" void kernel_launch(void* const* d_in, const int* in_sizes, int n_in,
                              void* d_out, int out_size, void* d_ws, size_t ws_size,
                              hipStream_t stream) {
  const float* feat = (const float*)d_in[0];
  const float* W    = (const float*)d_in[1];
  const float* bias = (const float*)d_in[2];
  const int*   toks = (const int*)d_in[3];
  float* out = (float*)d_out;

  const size_t wbf_bytes = (size_t)NLANG * EMBED * FEAT * 2;      // 16 MiB

  if (ws_size >= wbf_bytes) {
    ushort_t* Wbf = (ushort_t*)d_ws;
    convert_w_kernel<<<512, 256, 0, stream>>>(W, Wbf);
    (void)hipFuncSetAttribute((const void*)grouped_gemm_fused,
                              hipFuncAttributeMaxDynamicSharedMemorySize, 81920);
    const int nblk = (SEQ * BATCH / 256) * (EMBED / 256);         // 1024
    grouped_gemm_fused<<<nblk, 512, 81920, stream>>>(feat, Wbf, bias, toks, out);
  } else {
    grouped_proj_fused<<<(SEQ * BATCH / 128) * (EMBED / 128), 256, 0, stream>>>(
        feat, W, bias, toks, out);
  }
}

// Round 9
// 254.142 us; speedup vs baseline: 1.2028x; 1.2028x over previous
//
#include <hip/hip_runtime.h>
#include <hip/hip_bf16.h>

#define SEQ   512
#define BATCH 128
#define FEAT  1024
#define EMBED 1024
#define NLANG 8

typedef __attribute__((ext_vector_type(8))) short bf16x8;
typedef __attribute__((ext_vector_type(4))) float f32x4;
typedef unsigned short ushort_t;

__device__ __forceinline__ unsigned pk2(float a, float b) {
  float2 f; f.x = a; f.y = b;
  __hip_bfloat162 h = __float22bfloat162_rn(f);   // v_cvt_pk_bf16_f32
  union { __hip_bfloat162 h2; unsigned u; } cv;
  cv.h2 = h;
  return cv.u;
}

__device__ __forceinline__ bf16x8 cvt8(f32x4 lo, f32x4 hi) {
  union { bf16x8 v; unsigned u[4]; } q;
  q.u[0] = pk2(lo[0], lo[1]); q.u[1] = pk2(lo[2], lo[3]);
  q.u[2] = pk2(hi[0], hi[1]); q.u[3] = pk2(hi[2], hi[3]);
  return q.v;
}

__device__ __forceinline__ void gld16(const void* g, void* l) {
  __builtin_amdgcn_global_load_lds(
      (const __attribute__((address_space(1))) void*)g,
      (__attribute__((address_space(3))) void*)l, 16, 0, 0);
}

// ---------------- Pass 1 (W only): f32 -> bf16, linear. ~48 MB traffic. -----
__global__ __launch_bounds__(256) void convert_w_kernel(
    const float* __restrict__ Wf, ushort_t* __restrict__ Wbf)
{
  const int n = (NLANG * EMBED * FEAT) / 4;
  for (int c = blockIdx.x * 256 + threadIdx.x; c < n; c += gridDim.x * 256) {
    float4 v = ((const float4*)Wf)[c];
    uint2 o; o.x = pk2(v.x, v.y); o.y = pk2(v.z, v.w);
    *(uint2*)(Wbf + ((size_t)c << 2)) = o;
  }
}

// ---------------- Pass 2: fused grouped GEMM (R6 structure, A tile re-laid
// as 512 sub-rows x 64B to reproduce the R4-verified conflict-free bank
// geometry for f32 data). 256x256 tile, BK=32 granules, ring-3 A f32 (32KiB)
// + ring-3 B bf16 (16KiB) = 144 KiB, counted vmcnt(6), 2 phases x 16 MFMA,
// setprio. 512 threads = 8 waves (2M x 4N); per-wave 128x64 via acc[8][4]. ---
__global__ __launch_bounds__(512, 2) void grouped_gemm_fused(
    const float* __restrict__ feat,    // [S*B, F] f32 (original order)
    const ushort_t* __restrict__ Wbf,  // [L, E, F] bf16
    const float* __restrict__ bias,    // [L, E]
    const int*   __restrict__ toks,    // [B]
    float*       __restrict__ out)     // [S*B, E] original order
{
  extern __shared__ char ldsraw[];             // 147456 B dynamic
  float*    Af = (float*)ldsraw;               // 3 bufs x 8192 f32 (32 KiB)
  ushort_t* Bf = (ushort_t*)(ldsraw + 98304);  // 3 bufs x 8192 bf16 (16 KiB)
  __shared__ int tokarr[128];
  __shared__ unsigned long long ballots[2][8];
  __shared__ int perm[128];
  __shared__ int rowsrc[256];

  const int tid = threadIdx.x;
  const int l   = tid & 63;
  const int w   = tid >> 6;
  const int wr  = w >> 2;                    // 0..1 (M half)
  const int wc  = w & 3;                     // 0..3 (N quarter)

  // XCD-chunked bijective swizzle (1024 blocks = 8 XCDs x 128).
  const int bid = blockIdx.x;
  const int L   = (bid & 7) * 128 + (bid >> 3);
  const int et  = L & 3;
  const int mt  = (L >> 7) * 32 + ((L >> 2) & 31);
  const int m0  = mt * 256;
  const int e0  = et * 256;

  // ---- bucket setup (ballot histogram + rank; waves 0,1 vote) ----
  if (tid < 128) tokarr[tid] = toks[tid];
  __syncthreads();
  if (tid < 128) {
    int myt = tokarr[tid];
#pragma unroll
    for (int lg = 0; lg < 8; ++lg) {
      unsigned long long bl = __ballot(myt == lg);
      if (l == 0) ballots[w][lg] = bl;
    }
  }
  __syncthreads();

  int lsel = 0, base = 0, csel = 1, boff_sel = 0;
  {
    int cum = 0, boff = 0;
#pragma unroll
    for (int lg = 0; lg < 8; ++lg) {
      int c = __popcll(ballots[0][lg]) + __popcll(ballots[1][lg]);
      int seg = c << 9;
      bool in = (m0 >= cum) && (m0 < cum + seg);
      if (in) { lsel = lg; base = cum; csel = c; boff_sel = boff; }
      cum += seg; boff += c;
    }
  }

  if (tid < 128) {
    int myt = tokarr[tid];
    unsigned long long ltm = (1ull << l) - 1ull;
    int rank = (w == 0) ? __popcll(ballots[0][myt] & ltm)
                        : __popcll(ballots[0][myt]) + __popcll(ballots[1][myt] & ltm);
    int boff2 = 0;
#pragma unroll
    for (int lg = 0; lg < 8; ++lg) {
      int c = __popcll(ballots[0][lg]) + __popcll(ballots[1][lg]);
      boff2 += (lg < myt) ? c : 0;
    }
    perm[boff2 + rank] = tid;
  }
  __syncthreads();
  if (tid < 256) {
    int local = m0 - base + tid;
    int s = local / csel;
    int j = local - s * csel;
    rowsrc[tid] = s * BATCH + perm[boff_sel + j];
  }
  __syncthreads();

  // ---- A staging: granule = 256 rows x 32 f32 = 32 KiB, stored as 512
  // sub-rows x 64B: logical (row r, k-half h, chunk cc of 4 f32) lives at LDS
  // chunk (r + 256h)*4 + (cc ^ key), key = (r>>1)&3  [64B-row geometry = the
  // R4-verified conflict-free family]. gld16 dest LINEAR in c_lds = lane-seq;
  // the permutation is folded into the per-lane GLOBAL source (rule #21):
  //   c_lds -> h = c>>10, r = (c>>2)&255, key = (c>>3)&3, cc = (c&3)^key.
  // (checked: c=0 -> r0 k0-3; c=9 -> r2 chunk1 holds k0-3; c=1030 -> subrow
  //  257 chunk2 holds r1 k24-27 — read side agrees.) ----
  const float* aSrc[4];
#pragma unroll
  for (int i = 0; i < 4; ++i) {
    const int c   = (w * 4 + i) * 64 + l;
    const int h   = c >> 10;
    const int rr  = (c >> 2) & 255;
    const int key = (c >> 3) & 3;
    const int cc  = (c & 3) ^ key;
    aSrc[i] = feat + (size_t)rowsrc[rr] * FEAT + h * 16 + cc * 4;
  }
  const int aD0 = w * 1024;              // f32 units within an A buf (linear)
  const int aD1 = aD0 + 256;
  const int aD2 = aD0 + 512;
  const int aD3 = aD0 + 768;

  // ---- B staging (R4-verified): granule = 256 rows x 32 bf16 = 16 KiB =
  // 1024 chunks; c = row*4 + cc; src chunk = cc ^ ((row>>1)&3). ----
  const int ca  = w * 128 + l;
  const int rwB = ca >> 2;
  const int ccB = ca & 3;
  const int sB  = (rwB >> 1) & 3;
  const ushort_t* bS0 = Wbf + ((size_t)lsel * EMBED + e0 + rwB) * FEAT + ((ccB ^ sB) * 8);
  const ushort_t* bS1 = bS0 + (size_t)16 * FEAT;
  const int bD0 = (w * 128) * 8;         // ushort units within a B buf
  const int bD1 = (w * 128 + 64) * 8;

  // ---- fragment read offsets ----
  // A (f32, new geometry): fragment (r = wr*128+mf*16+(l&15), kc = l>>4)
  // needs k = kc*8..kc*8+7: h = kc>>1, chunks cb=(kc&1)*2, cb+1 of sub-row
  // r+256h, swizzled ^key, key = ((l&15)>>1)&3 (r's low bits = l&15).
  // Within a 16-lane phase: sub-row parity alternates -> 2 lanes/bank-quad.
  const int kc    = l >> 4;
  const int keyA  = ((l & 15) >> 1) & 3;
  const int cbA   = (kc & 1) * 2;
  const int baseA = (wr * 128 + (l & 15)) * 16 + 4096 * (kc >> 1);  // f32 units
  const int sLo   = (cbA ^ keyA) * 4;
  const int sHi   = ((cbA + 1) ^ keyA) * 4;
  // B (bf16): as R4.
  const int rB  = wc * 64 + (l & 15);
  const int bRd = rB * 32 + ((kc ^ ((rB >> 1) & 3)) * 8);  // ushort units

  f32x4 acc[8][4] = {};
  bf16x8 af0[4], af1[4], bfq[4];

#define STAGE_A(kt, buf)                                                   \
  do { const int _o = (kt) * 32;                                           \
    gld16(aSrc[0] + _o, Af + (buf) * 8192 + aD0);                          \
    gld16(aSrc[1] + _o, Af + (buf) * 8192 + aD1);                          \
    gld16(aSrc[2] + _o, Af + (buf) * 8192 + aD2);                          \
    gld16(aSrc[3] + _o, Af + (buf) * 8192 + aD3); } while (0)
#define STAGE_B(kt, buf)                                                   \
  do { const int _o = (kt) * 32;                                           \
    gld16(bS0 + _o, Bf + (buf) * 8192 + bD0);                              \
    gld16(bS1 + _o, Bf + (buf) * 8192 + bD1); } while (0)

// Phase 0 of granule g: read+cvt A m-half0, read all B, stage A(g+2),
// MFMA acc[0..3]. rbuf/sbuf compile-time ring indices (g%3, (g+2)%3).
#define PH0(g, rbuf, sbuf, DOSTAGE)                                        \
  do {                                                                     \
    const float*    Ab_ = Af + (rbuf) * 8192;                              \
    const ushort_t* Bb_ = Bf + (rbuf) * 8192;                              \
    _Pragma("unroll") for (int mf = 0; mf < 4; ++mf) {                     \
      f32x4 lo_ = *(const f32x4*)(Ab_ + baseA + mf * 256 + sLo);           \
      f32x4 hi_ = *(const f32x4*)(Ab_ + baseA + mf * 256 + sHi);           \
      af0[mf] = cvt8(lo_, hi_);                                            \
    }                                                                      \
    _Pragma("unroll") for (int nf = 0; nf < 4; ++nf)                       \
      bfq[nf] = *(const bf16x8*)(Bb_ + bRd + nf * 512);                    \
    if (DOSTAGE) { STAGE_A((g) + 2, sbuf); }                               \
    __builtin_amdgcn_sched_barrier(0);                                     \
    __builtin_amdgcn_s_barrier();                                          \
    asm volatile("s_waitcnt lgkmcnt(0)" ::: "memory");                     \
    __builtin_amdgcn_sched_barrier(0);                                     \
    __builtin_amdgcn_s_setprio(1);                                         \
    _Pragma("unroll") for (int mf = 0; mf < 4; ++mf)                       \
        _Pragma("unroll") for (int nf = 0; nf < 4; ++nf)                   \
            acc[mf][nf] = __builtin_amdgcn_mfma_f32_16x16x32_bf16(         \
                af0[mf], bfq[nf], acc[mf][nf], 0, 0, 0);                   \
    __builtin_amdgcn_s_setprio(0);                                         \
    __builtin_amdgcn_s_barrier();                                          \
  } while (0)

// Phase 1 of granule g: read+cvt A m-half1, stage B(g+2), MFMA acc[4..7],
// counted vmcnt (WAIT) before closing barrier.
#define PH1(g, rbuf, sbuf, DOSTAGE, WAIT)                                  \
  do {                                                                     \
    const float* Ab_ = Af + (rbuf) * 8192;                                 \
    _Pragma("unroll") for (int mf = 0; mf < 4; ++mf) {                     \
      f32x4 lo_ = *(const f32x4*)(Ab_ + baseA + (mf + 4) * 256 + sLo);     \
      f32x4 hi_ = *(const f32x4*)(Ab_ + baseA + (mf + 4) * 256 + sHi);     \
      af1[mf] = cvt8(lo_, hi_);                                            \
    }                                                                      \
    if (DOSTAGE) { STAGE_B((g) + 2, sbuf); }                               \
    __builtin_amdgcn_sched_barrier(0);                                     \
    __builtin_amdgcn_s_barrier();                                          \
    asm volatile("s_waitcnt lgkmcnt(0)" ::: "memory");                     \
    __builtin_amdgcn_sched_barrier(0);                                     \
    __builtin_amdgcn_s_setprio(1);                                         \
    _Pragma("unroll") for (int mf = 0; mf < 4; ++mf)                       \
        _Pragma("unroll") for (int nf = 0; nf < 4; ++nf)                   \
            acc[mf + 4][nf] = __builtin_amdgcn_mfma_f32_16x16x32_bf16(     \
                af1[mf], bfq[nf], acc[mf + 4][nf], 0, 0, 0);               \
    __builtin_amdgcn_s_setprio(0);                                         \
    asm volatile(WAIT ::: "memory");                                       \
    __builtin_amdgcn_s_barrier();                                          \
  } while (0)

  // prologue: stage granules 0,1 (12 loads); vmcnt(6) -> granule 0 resident.
  STAGE_A(0, 0); STAGE_B(0, 0);
  STAGE_A(1, 1); STAGE_B(1, 1);
  asm volatile("s_waitcnt vmcnt(6)" ::: "memory");
  __builtin_amdgcn_s_barrier();
  __builtin_amdgcn_sched_barrier(0);

  // steady state (ring-3): granule g reads buf g%3, stages g+2 into (g+2)%3.
  // vmcnt(6) at granule end retires g+1's 6 loads (g+2's 6 remain).
#pragma unroll 1
  for (int gg = 0; gg < 10; ++gg) {
    const int g = gg * 3;
    PH0(g + 0, 0, 2, true);  PH1(g + 0, 0, 2, true, "s_waitcnt vmcnt(6)");
    PH0(g + 1, 1, 0, true);  PH1(g + 1, 1, 0, true, "s_waitcnt vmcnt(6)");
    PH0(g + 2, 2, 1, true);  PH1(g + 2, 2, 1, true, "s_waitcnt vmcnt(6)");
  }
  // tail: granule 30 (buf 0), drain; granule 31 (buf 1).
  PH0(30, 0, 0, false); PH1(30, 0, 0, false, "s_waitcnt vmcnt(0)");
  PH0(31, 1, 0, false); PH1(31, 1, 0, false, "s_nop 0");

#undef PH0
#undef PH1
#undef STAGE_A
#undef STAGE_B

  // ---- epilogue: C/D col = lane&15 (-> e), row = (lane>>4)*4+j (-> m) ----
  const int col = l & 15;
  const int r4  = (l >> 4) * 4;
  float bvv[4];
#pragma unroll
  for (int nf = 0; nf < 4; ++nf)
    bvv[nf] = bias[lsel * EMBED + e0 + wc * 64 + nf * 16 + col];
#pragma unroll
  for (int mf = 0; mf < 8; ++mf) {
#pragma unroll
    for (int j = 0; j < 4; ++j) {
      const size_t ro = (size_t)rowsrc[wr * 128 + mf * 16 + r4 + j] * EMBED;
#pragma unroll
      for (int nf = 0; nf < 4; ++nf)
        out[ro + e0 + wc * 64 + nf * 16 + col] = acc[mf][nf][j] + bvv[nf];
    }
  }
}

// ---------------- Fallback (R2 fused kernel) if ws too small ----------------
__global__ __launch_bounds__(256, 2) void grouped_proj_fused(
    const float* __restrict__ feat, const float* __restrict__ Wt,
    const float* __restrict__ bias, const int* __restrict__ toks,
    float* __restrict__ out)
{
  __shared__ uint4 As[1024];
  __shared__ uint4 Bs[1024];
  __shared__ int tokarr[128];
  __shared__ unsigned long long ballots[2][8];
  __shared__ int perm[128];
  __shared__ int rowsrc[128];

  const int tid  = threadIdx.x;
  const int lane = tid & 63;
  const int wv   = tid >> 6;
  const int wr   = wv >> 1;
  const int wc   = wv & 1;
  const int bid = blockIdx.x;
  const int xcd = bid & 7;
  const int sq  = bid >> 3;
  const int et  = sq & 7;
  const int mt  = (sq >> 3) * 8 + xcd;
  const int m0  = mt * 128;
  const int e0  = et * 128;

  if (tid < 128) tokarr[tid] = toks[tid];
  __syncthreads();
  if (tid < 128) {
    int myt = tokarr[tid];
#pragma unroll
    for (int lg = 0; lg < 8; ++lg) {
      unsigned long long bl = __ballot(myt == lg);
      if (lane == 0) ballots[wv][lg] = bl;
    }
  }
  __syncthreads();
  int lsel = 0, base = 0, csel = 1, boff_sel = 0;
  {
    int cum = 0, boff = 0;
#pragma unroll
    for (int lg = 0; lg < 8; ++lg) {
      int c = __popcll(ballots[0][lg]) + __popcll(ballots[1][lg]);
      int seg = c << 9;
      bool in = (m0 >= cum) && (m0 < cum + seg);
      if (in) { lsel = lg; base = cum; csel = c; boff_sel = boff; }
      cum += seg; boff += c;
    }
  }
  if (tid < 128) {
    int myt = tokarr[tid];
    unsigned long long ltm = (1ull << lane) - 1ull;
    int rank = (wv == 0) ? __popcll(ballots[0][myt] & ltm)
                         : __popcll(ballots[0][myt]) + __popcll(ballots[1][myt] & ltm);
    int boff2 = 0;
#pragma unroll
    for (int lg = 0; lg < 8; ++lg) {
      int c = __popcll(ballots[0][lg]) + __popcll(ballots[1][lg]);
      boff2 += (lg < myt) ? c : 0;
    }
    perm[boff2 + rank] = tid;
  }
  __syncthreads();
  if (tid < 128) {
    int local = m0 - base + tid;
    int s = local / csel;
    int j = local - s * csel;
    rowsrc[tid] = s * BATCH + perm[boff_sel + j];
  }
  __syncthreads();

  int slot_i[4];
  const float* aptr[4];
  const float* bptr[4];
#pragma unroll
  for (int it = 0; it < 4; ++it) {
    int c    = it * 256 + tid;
    int kg   = c & 7;
    int row  = c >> 3;
    int ksub = kg & 3;
    int kk   = kg >> 2;
    int frag = row >> 4;
    slot_i[it] = (kk * 8 + frag) * 64 + ((row & 15) ^ (ksub << 1) ^ kk) + ksub * 16;
    aptr[it] = feat + (size_t)rowsrc[row] * FEAT + kg * 8;
    bptr[it] = Wt + ((size_t)lsel * EMBED + e0 + row) * FEAT + kg * 8;
  }

  f32x4 acc[4][4] = {};
  for (int k0 = 0; k0 < FEAT; k0 += 64) {
    __syncthreads();
#pragma unroll
    for (int it = 0; it < 4; ++it) {
      float4 alo = *(const float4*)(aptr[it] + k0);
      float4 ahi = *(const float4*)(aptr[it] + k0 + 4);
      uint4 av;
      av.x = pk2(alo.x, alo.y); av.y = pk2(alo.z, alo.w);
      av.z = pk2(ahi.x, ahi.y); av.w = pk2(ahi.z, ahi.w);
      As[slot_i[it]] = av;
      float4 blo = *(const float4*)(bptr[it] + k0);
      float4 bhi = *(const float4*)(bptr[it] + k0 + 4);
      uint4 bv;
      bv.x = pk2(blo.x, blo.y); bv.y = pk2(blo.z, blo.w);
      bv.z = pk2(bhi.x, bhi.y); bv.w = pk2(bhi.z, bhi.w);
      Bs[slot_i[it]] = bv;
    }
    __syncthreads();
#pragma unroll
    for (int kk = 0; kk < 2; ++kk) {
      const int ksr = lane >> 4;
      const int sw  = ((lane & 15) ^ (ksr << 1) ^ kk) + ksr * 16;
      bf16x8 af[4], bfr[4];
#pragma unroll
      for (int mi = 0; mi < 4; ++mi)
        af[mi] = ((const bf16x8*)As)[(kk * 8 + wr * 4 + mi) * 64 + sw];
#pragma unroll
      for (int ni = 0; ni < 4; ++ni)
        bfr[ni] = ((const bf16x8*)Bs)[(kk * 8 + wc * 4 + ni) * 64 + sw];
#pragma unroll
      for (int mi = 0; mi < 4; ++mi)
#pragma unroll
        for (int ni = 0; ni < 4; ++ni)
          acc[mi][ni] = __builtin_amdgcn_mfma_f32_16x16x32_bf16(
              af[mi], bfr[ni], acc[mi][ni], 0, 0, 0);
    }
  }

  const int col = lane & 15;
  const int r0  = (lane >> 4) * 4;
  float bvv[4];
#pragma unroll
  for (int ni = 0; ni < 4; ++ni)
    bvv[ni] = bias[lsel * EMBED + e0 + wc * 64 + ni * 16 + col];
#pragma unroll
  for (int mi = 0; mi < 4; ++mi) {
#pragma unroll
    for (int j = 0; j < 4; ++j) {
      const size_t ro = (size_t)rowsrc[wr * 64 + mi * 16 + r0 + j] * EMBED;
#pragma unroll
      for (int ni = 0; ni < 4; ++ni)
        out[ro + e0 + wc * 64 + ni * 16 + col] = acc[mi][ni][j] + bvv[ni];
    }
  }
}

extern "C" void kernel_launch(void* const* d_in, const int* in_sizes, int n_in,
                              void* d_out, int out_size, void* d_ws, size_t ws_size,
                              hipStream_t stream) {
  const float* feat = (const float*)d_in[0];
  const float* W    = (const float*)d_in[1];
  const float* bias = (const float*)d_in[2];
  const int*   toks = (const int*)d_in[3];
  float* out = (float*)d_out;

  const size_t wbf_bytes = (size_t)NLANG * EMBED * FEAT * 2;      // 16 MiB

  if (ws_size >= wbf_bytes) {
    ushort_t* Wbf = (ushort_t*)d_ws;
    convert_w_kernel<<<512, 256, 0, stream>>>(W, Wbf);
    (void)hipFuncSetAttribute((const void*)grouped_gemm_fused,
                              hipFuncAttributeMaxDynamicSharedMemorySize, 147456);
    const int nblk = (SEQ * BATCH / 256) * (EMBED / 256);         // 1024
    grouped_gemm_fused<<<nblk, 512, 147456, stream>>>(feat, Wbf, bias, toks, out);
  } else {
    grouped_proj_fused<<<(SEQ * BATCH / 128) * (EMBED / 128), 256, 0, stream>>>(
        feat, W, bias, toks, out);
  }
}